// Round 3
// baseline (17865.988 us; speedup 1.0000x reference)
//
#include <hip/hip_runtime.h>
#include <math.h>

// Problem constants
constexpr int B = 32, S = 128, H = 768, L = 12, NH = 12, FF = 3072, T = 9;
constexpr int DH = 64, SP = 127;
constexpr int P1 = 382, P2 = 189;

// ---------------- reductions ----------------
__device__ __forceinline__ float waveSum(float v) {
#pragma unroll
  for (int o = 32; o > 0; o >>= 1) v += __shfl_xor(v, o, 64);
  return v;
}
__device__ __forceinline__ float waveMax(float v) {
#pragma unroll
  for (int o = 32; o > 0; o >>= 1) v = fmaxf(v, __shfl_xor(v, o, 64));
  return v;
}
template <int NW>
__device__ __forceinline__ float blockSum(float v, float* sh) {
  v = waveSum(v);
  int w = threadIdx.x >> 6;
  if ((threadIdx.x & 63) == 0) sh[w] = v;
  __syncthreads();
  float s = 0.0f;
#pragma unroll
  for (int i = 0; i < NW; i++) s += sh[i];
  __syncthreads();
  return s;
}
template <int NW>
__device__ __forceinline__ float blockMax(float v, float* sh) {
  v = waveMax(v);
  int w = threadIdx.x >> 6;
  if ((threadIdx.x & 63) == 0) sh[w] = v;
  __syncthreads();
  float s = -3.0e38f;
#pragma unroll
  for (int i = 0; i < NW; i++) s = fmaxf(s, sh[i]);
  __syncthreads();
  return s;
}

// ---------------- embedding + LN ----------------
__global__ __launch_bounds__(256) void embed_ln_kernel(
    const int* __restrict__ ids, const int* __restrict__ tt,
    const float* __restrict__ tok, const float* __restrict__ pos,
    const float* __restrict__ typ, const float* __restrict__ g,
    const float* __restrict__ bb, float* __restrict__ x) {
  int token = blockIdx.x;          // b*S + s
  int s = token & (S - 1);
  __shared__ float buf[H];
  __shared__ float red[4];
  int id = ids[token], t = tt[token];
  for (int m = threadIdx.x; m < H; m += 256)
    buf[m] = tok[(size_t)id * H + m] + pos[s * H + m] + typ[t * H + m];
  __syncthreads();
  float ls = 0.0f;
  for (int m = threadIdx.x; m < H; m += 256) ls += buf[m];
  float mean = blockSum<4>(ls, red) * (1.0f / H);
  float lv = 0.0f;
  for (int m = threadIdx.x; m < H; m += 256) {
    float d = buf[m] - mean;
    lv += d * d;
  }
  float var = blockSum<4>(lv, red) * (1.0f / H);
  float inv = rsqrtf(var + 1e-12f);
  for (int m = threadIdx.x; m < H; m += 256)
    x[(size_t)token * H + m] = (buf[m] - mean) * inv * g[m] + bb[m];
}

// ---------------- residual add + LN ----------------
__global__ __launch_bounds__(256) void add_ln_kernel(
    const float* __restrict__ a, const float* __restrict__ c,
    const float* __restrict__ g, const float* __restrict__ bb,
    float* __restrict__ out) {
  int token = blockIdx.x;
  __shared__ float buf[H];
  __shared__ float red[4];
  for (int m = threadIdx.x; m < H; m += 256)
    buf[m] = a[(size_t)token * H + m] + c[(size_t)token * H + m];
  __syncthreads();
  float ls = 0.0f;
  for (int m = threadIdx.x; m < H; m += 256) ls += buf[m];
  float mean = blockSum<4>(ls, red) * (1.0f / H);
  float lv = 0.0f;
  for (int m = threadIdx.x; m < H; m += 256) {
    float d = buf[m] - mean;
    lv += d * d;
  }
  float var = blockSum<4>(lv, red) * (1.0f / H);
  float inv = rsqrtf(var + 1e-12f);
  for (int m = threadIdx.x; m < H; m += 256)
    out[(size_t)token * H + m] = (buf[m] - mean) * inv * g[m] + bb[m];
}

// ---------------- fp32 tiled GEMM: C = A(M,K) @ W(K,N) + bias, act=1 -> exact GELU ----
__global__ __launch_bounds__(256) void gemm_kernel(
    const float* __restrict__ A, const float* __restrict__ W,
    const float* __restrict__ bias, float* __restrict__ C,
    int M, int N, int K, int act) {
  __shared__ float As[16][65];
  __shared__ float Bs[16][65];
  int bn = blockIdx.x * 64, bm = blockIdx.y * 64;
  int tid = threadIdx.x;
  int tx = tid & 15, ty = tid >> 4;
  float acc[4][4];
#pragma unroll
  for (int i = 0; i < 4; i++)
#pragma unroll
    for (int j = 0; j < 4; j++) acc[i][j] = 0.0f;
  int arow = tid >> 4, acol = tid & 15;
  int wrow = tid >> 6, wcol = tid & 63;
  for (int k0 = 0; k0 < K; k0 += 16) {
#pragma unroll
    for (int r = 0; r < 4; r++)
      As[acol][arow + r * 16] = A[(size_t)(bm + arow + r * 16) * K + k0 + acol];
#pragma unroll
    for (int r = 0; r < 4; r++)
      Bs[wrow + r * 4][wcol] = W[(size_t)(k0 + wrow + r * 4) * N + bn + wcol];
    __syncthreads();
#pragma unroll
    for (int kk = 0; kk < 16; kk++) {
      float av[4], bv[4];
#pragma unroll
      for (int i = 0; i < 4; i++) av[i] = As[kk][ty * 4 + i];
#pragma unroll
      for (int j = 0; j < 4; j++) bv[j] = Bs[kk][tx * 4 + j];
#pragma unroll
      for (int i = 0; i < 4; i++)
#pragma unroll
        for (int j = 0; j < 4; j++) acc[i][j] += av[i] * bv[j];
    }
    __syncthreads();
  }
#pragma unroll
  for (int i = 0; i < 4; i++) {
    int row = bm + ty * 4 + i;
#pragma unroll
    for (int j = 0; j < 4; j++) {
      int col = bn + tx * 4 + j;
      float v = acc[i][j] + bias[col];
      if (act) v = 0.5f * v * (1.0f + erff(v * 0.7071067811865476f));
      C[(size_t)row * N + col] = v;
    }
  }
}

// ---------------- attention: one block per (q, head, batch) ----------------
__global__ __launch_bounds__(128) void attn_kernel(
    const float* __restrict__ qkv, const int* __restrict__ amask,
    float* __restrict__ out) {
  int q = blockIdx.x, h = blockIdx.y, b = blockIdx.z;
  __shared__ float qv[DH];
  __shared__ float p[S];
  __shared__ float red[2];
  int tid = threadIdx.x;
  const float* base = qkv + (size_t)b * S * 3 * H;
  if (tid < DH) qv[tid] = base[(size_t)q * 3 * H + h * DH + tid];
  __syncthreads();
  const float* krow = base + (size_t)tid * 3 * H + H + h * DH;
  float sc = 0.0f;
#pragma unroll 16
  for (int d = 0; d < DH; d++) sc += qv[d] * krow[d];
  sc = sc * 0.125f + (amask[b * S + tid] ? 0.0f : -1e9f);
  float mx = blockMax<2>(sc, red);
  float e = expf(sc - mx);
  float sum = blockSum<2>(e, red);
  p[tid] = e / sum;
  __syncthreads();
  if (tid < DH) {
    const float* vb = base + 2 * H + h * DH + tid;
    float o = 0.0f;
    for (int j = 0; j < S; j++) o += p[j] * vb[(size_t)j * 3 * H];
    out[((size_t)b * S + q) * H + h * DH + tid] = o;
  }
}

// ---------------- conv1: (B,127,768) -> (B,127,382), k=5, stride 2 ----------------
__global__ __launch_bounds__(128) void conv1_kernel(
    const float* __restrict__ x, const float* __restrict__ w,
    const float* __restrict__ bias, float* __restrict__ c1) {
  int p = blockIdx.x, b = blockIdx.y;
  __shared__ float tile[SP * 5];
  for (int idx = threadIdx.x; idx < SP * 5; idx += 128) {
    int i = idx / 5, k = idx % 5;
    tile[idx] = x[((size_t)b * S + (i + 1)) * H + 2 * p + k];
  }
  __syncthreads();
  int o = threadIdx.x;
  if (o < SP) {
    const float* wr = w + (size_t)o * SP * 5;
    float acc = bias[o];
    for (int ik = 0; ik < SP * 5; ik++) acc += wr[ik] * tile[ik];
    c1[((size_t)b * SP + o) * P1 + p] = acc;
  }
}

// ---------------- conv2: (B,127,382) -> (B,127,189), k=3, stride 2, dilation 2 ----
__global__ __launch_bounds__(128) void conv2_kernel(
    const float* __restrict__ c1, const float* __restrict__ w,
    const float* __restrict__ bias, float* __restrict__ c2) {
  int p = blockIdx.x, b = blockIdx.y;
  __shared__ float tile[SP * 3];
  for (int idx = threadIdx.x; idx < SP * 3; idx += 128) {
    int i = idx / 3, k = idx % 3;
    tile[idx] = c1[((size_t)b * SP + i) * P1 + 2 * p + 2 * k];
  }
  __syncthreads();
  int o = threadIdx.x;
  if (o < SP) {
    const float* wr = w + (size_t)o * SP * 3;
    float acc = bias[o];
    for (int ik = 0; ik < SP * 3; ik++) acc += wr[ik] * tile[ik];
    c2[((size_t)b * SP + o) * P2 + p] = acc;
  }
}

// ---------------- linear: (B*127,189) @ (189,9) + b ----------------
__global__ __launch_bounds__(64) void linear_kernel(
    const float* __restrict__ c2, const float* __restrict__ w,
    const float* __restrict__ bias, float* __restrict__ logits) {
  int row = blockIdx.x;  // b*SP + o
  int t = threadIdx.x;
  if (t < T) {
    const float* cr = c2 + (size_t)row * P2;
    float acc = bias[t];
    for (int p = 0; p < P2; p++) acc += cr[p] * w[p * T + t];
    logits[(size_t)row * T + t] = acc;
  }
}

// ---------------- CRF: forward-logsumexp + Viterbi + gold score, per batch ----------
__global__ __launch_bounds__(64) void crf_kernel(
    const float* __restrict__ em, const int* __restrict__ amask,
    const int* __restrict__ y, const float* __restrict__ start,
    const float* __restrict__ endv, const float* __restrict__ trans,
    float* __restrict__ path_out, float* __restrict__ part) {
  int b = blockIdx.x;
  int tid = threadIdx.x;
  __shared__ float sn[T], sv[T], nn[T], nv[T], e_sh[T];
  __shared__ float tr[T * T];
  __shared__ int hist[(SP - 1) * T];
  const float* eb = em + (size_t)b * SP * T;
  // T*T = 81 > 64 threads: MUST loop (round-1 bug: tr[64..80] was garbage)
  for (int i = tid; i < T * T; i += 64) tr[i] = trans[i];
  if (tid < T) {
    sn[tid] = start[tid] + eb[tid];
    sv[tid] = sn[tid];
  }
  __syncthreads();
  for (int t = 1; t < SP; t++) {
    int m = amask[b * S + t + 1];  // mask_sp[b, t]
    if (tid < T) e_sh[tid] = eb[t * T + tid];
    __syncthreads();
    if (tid < T) {
      int j = tid;
      float vals[T];
      float mx = -3.0e38f;
#pragma unroll
      for (int i = 0; i < T; i++) {
        float v = sn[i] + tr[i * T + j];
        vals[i] = v;
        mx = fmaxf(mx, v);
      }
      float sm = 0.0f;
#pragma unroll
      for (int i = 0; i < T; i++) sm += expf(vals[i] - mx);
      float ns = mx + logf(sm) + e_sh[j];
      float best = -3.0e38f;
      int bi = 0;
#pragma unroll
      for (int i = 0; i < T; i++) {
        float v = sv[i] + tr[i * T + j];
        if (v > best) { best = v; bi = i; }  // strict > keeps lowest index (jnp.argmax)
      }
      float nvv = best + e_sh[j];
      nn[j] = m ? ns : sn[j];
      nv[j] = m ? nvv : sv[j];
      hist[(t - 1) * T + j] = m ? bi : j;
    }
    __syncthreads();
    if (tid < T) {
      sn[tid] = nn[tid];
      sv[tid] = nv[tid];
    }
    __syncthreads();
  }
  if (tid == 0) {
    // norm = logsumexp(sn + end)
    float mx = -3.0e38f;
    for (int j = 0; j < T; j++) mx = fmaxf(mx, sn[j] + endv[j]);
    float sm = 0.0f;
    for (int j = 0; j < T; j++) sm += expf(sn[j] + endv[j] - mx);
    float norm = mx + logf(sm);
    // viterbi terminal + backtrack
    float bestv = -3.0e38f;
    int last = 0;
    for (int j = 0; j < T; j++) {
      float v = sv[j] + endv[j];
      if (v > bestv) { bestv = v; last = j; }
    }
    int tag = last;
    for (int t = SP - 2; t >= 0; t--) {
      path_out[(size_t)b * SP + t + 1] = (float)tag;
      tag = hist[t * T + tag];
    }
    path_out[(size_t)b * SP] = (float)tag;
    // gold score
    const int* tg = y + b * SP;
    float sc = start[tg[0]] + eb[tg[0]];
    int length = 0;
    for (int t = 0; t < SP; t++) length += (amask[b * S + t + 1] != 0);
    for (int t = 1; t < SP; t++) {
      if (amask[b * S + t + 1])
        sc += tr[tg[t - 1] * T + tg[t]] + eb[t * T + tg[t]];
    }
    sc += endv[tg[length - 1]];
    part[b] = sc - norm;
  }
}

__global__ __launch_bounds__(64) void finalize_kernel(const float* __restrict__ part,
                                                      float* __restrict__ out) {
  float v = (threadIdx.x < B) ? part[threadIdx.x] : 0.0f;
  v = waveSum(v);
  if (threadIdx.x == 0) out[0] = v * (1.0f / B);
}

// ---------------- host launcher ----------------
extern "C" void kernel_launch(void* const* d_in, const int* in_sizes, int n_in,
                              void* d_out, int out_size, void* d_ws, size_t ws_size,
                              hipStream_t stream) {
  const int* input_ids = (const int*)d_in[0];
  const int* amask = (const int*)d_in[1];
  const int* tt = (const int*)d_in[2];
  const int* y_true = (const int*)d_in[3];
  const float* tok_emb = (const float*)d_in[4];
  const float* pos_emb = (const float*)d_in[5];
  const float* type_emb = (const float*)d_in[6];
  const float* emb_g = (const float*)d_in[7];
  const float* emb_b = (const float*)d_in[8];
  const float* Wqkv = (const float*)d_in[9];
  const float* bqkv = (const float*)d_in[10];
  const float* Wo = (const float*)d_in[11];
  const float* bo = (const float*)d_in[12];
  const float* ln1g = (const float*)d_in[13];
  const float* ln1b = (const float*)d_in[14];
  const float* Wff1 = (const float*)d_in[15];
  const float* bff1 = (const float*)d_in[16];
  const float* Wff2 = (const float*)d_in[17];
  const float* bff2 = (const float*)d_in[18];
  const float* ln2g = (const float*)d_in[19];
  const float* ln2b = (const float*)d_in[20];
  const float* c1w = (const float*)d_in[21];
  const float* c1b = (const float*)d_in[22];
  const float* c2w = (const float*)d_in[23];
  const float* c2b = (const float*)d_in[24];
  const float* lw = (const float*)d_in[25];
  const float* lb = (const float*)d_in[26];
  const float* crf_s = (const float*)d_in[27];
  const float* crf_e = (const float*)d_in[28];
  const float* crf_t = (const float*)d_in[29];

  char* ws = (char*)d_ws;
  const size_t sx = (size_t)B * S * H * sizeof(float);       // 12.58 MB
  const size_t sff = (size_t)B * S * FF * sizeof(float);     // 50.33 MB
  float* x = (float*)(ws);                                   // layer input/output
  float* hmid = (float*)(ws + sx);                           // post-attn LN
  float* bigA = (float*)(ws + 2 * sx);                       // qkv (37.7MB) / ff1 (50.3MB)
  float* bufB = (float*)(ws + 2 * sx + sff);                 // attn_o / ff2
  float* bufC = (float*)(ws + 3 * sx + sff);                 // proj
  // post-transformer reuse of bigA:
  float* c1 = bigA;                                          // 6.21 MB
  float* c2 = (float*)((char*)bigA + (size_t)B * SP * P1 * sizeof(float));
  float* logits = (float*)((char*)c2 + (size_t)B * SP * P2 * sizeof(float));
  float* part = (float*)((char*)logits + (size_t)B * SP * T * sizeof(float));

  float* outf = (float*)d_out;

  embed_ln_kernel<<<B * S, 256, 0, stream>>>(input_ids, tt, tok_emb, pos_emb,
                                             type_emb, emb_g, emb_b, x);
  for (int l = 0; l < L; l++) {
    gemm_kernel<<<dim3(3 * H / 64, B * S / 64), 256, 0, stream>>>(
        x, Wqkv + (size_t)l * H * 3 * H, bqkv + (size_t)l * 3 * H, bigA,
        B * S, 3 * H, H, 0);
    attn_kernel<<<dim3(S, NH, B), 128, 0, stream>>>(bigA, amask, bufB);
    gemm_kernel<<<dim3(H / 64, B * S / 64), 256, 0, stream>>>(
        bufB, Wo + (size_t)l * H * H, bo + (size_t)l * H, bufC, B * S, H, H, 0);
    add_ln_kernel<<<B * S, 256, 0, stream>>>(x, bufC, ln1g + (size_t)l * H,
                                             ln1b + (size_t)l * H, hmid);
    gemm_kernel<<<dim3(FF / 64, B * S / 64), 256, 0, stream>>>(
        hmid, Wff1 + (size_t)l * H * FF, bff1 + (size_t)l * FF, bigA,
        B * S, FF, H, 1);
    gemm_kernel<<<dim3(H / 64, B * S / 64), 256, 0, stream>>>(
        bigA, Wff2 + (size_t)l * FF * H, bff2 + (size_t)l * H, bufB,
        B * S, H, FF, 0);
    add_ln_kernel<<<B * S, 256, 0, stream>>>(hmid, bufB, ln2g + (size_t)l * H,
                                             ln2b + (size_t)l * H, x);
  }
  conv1_kernel<<<dim3(P1, B), 128, 0, stream>>>(x, c1w, c1b, c1);
  conv2_kernel<<<dim3(P2, B), 128, 0, stream>>>(c1, c2w, c2b, c2);
  linear_kernel<<<B * SP, 64, 0, stream>>>(c2, lw, lb, logits);
  crf_kernel<<<B, 64, 0, stream>>>(logits, amask, y_true, crf_s, crf_e, crf_t,
                                   outf + 1, part);
  finalize_kernel<<<1, 64, 0, stream>>>(part, outf);
}

// Round 4
// 8040.672 us; speedup vs baseline: 2.2220x; 2.2220x over previous
//
#include <hip/hip_runtime.h>
#include <math.h>

// Problem constants
constexpr int B = 32, S = 128, H = 768, L = 12, NH = 12, FF = 3072, T = 9;
constexpr int DH = 64, SP = 127;
constexpr int P1 = 382, P2 = 189;

typedef __attribute__((ext_vector_type(8))) short short8;
typedef __attribute__((ext_vector_type(4))) short short4v;
typedef __attribute__((ext_vector_type(4))) float floatx4;

// fp32 -> bf16 (RNE) and hi/lo split: x ~= hi + lo, |err| ~ 2^-17 |x|
__device__ __forceinline__ unsigned short f2bf(float x) {
  unsigned u = __float_as_uint(x);
  u += 0x7FFFu + ((u >> 16) & 1u);
  return (unsigned short)(u >> 16);
}
__device__ __forceinline__ void split2(float x, unsigned short& h, unsigned short& l) {
  h = f2bf(x);
  float hf = __uint_as_float(((unsigned)h) << 16);
  l = f2bf(x - hf);
}

// ---------------- reductions ----------------
__device__ __forceinline__ float waveSum(float v) {
#pragma unroll
  for (int o = 32; o > 0; o >>= 1) v += __shfl_xor(v, o, 64);
  return v;
}
__device__ __forceinline__ float waveMax(float v) {
#pragma unroll
  for (int o = 32; o > 0; o >>= 1) v = fmaxf(v, __shfl_xor(v, o, 64));
  return v;
}
template <int NW>
__device__ __forceinline__ float blockSum(float v, float* sh) {
  v = waveSum(v);
  int w = threadIdx.x >> 6;
  if ((threadIdx.x & 63) == 0) sh[w] = v;
  __syncthreads();
  float s = 0.0f;
#pragma unroll
  for (int i = 0; i < NW; i++) s += sh[i];
  __syncthreads();
  return s;
}
template <int NW>
__device__ __forceinline__ float blockMax(float v, float* sh) {
  v = waveMax(v);
  int w = threadIdx.x >> 6;
  if ((threadIdx.x & 63) == 0) sh[w] = v;
  __syncthreads();
  float s = -3.0e38f;
#pragma unroll
  for (int i = 0; i < NW; i++) s = fmaxf(s, sh[i]);
  __syncthreads();
  return s;
}

// ---------------- embedding + LN (emits fp32 + bf16 hi/lo split) ----------------
__global__ __launch_bounds__(256) void embed_ln_kernel(
    const int* __restrict__ ids, const int* __restrict__ tt,
    const float* __restrict__ tok, const float* __restrict__ pos,
    const float* __restrict__ typ, const float* __restrict__ g,
    const float* __restrict__ bb, float* __restrict__ x,
    short* __restrict__ xh, short* __restrict__ xl) {
  int token = blockIdx.x;  // b*S + s
  int s = token & (S - 1);
  __shared__ float buf[H];
  __shared__ float red[4];
  int id = ids[token], t = tt[token];
  for (int m = threadIdx.x; m < H; m += 256)
    buf[m] = tok[(size_t)id * H + m] + pos[s * H + m] + typ[t * H + m];
  __syncthreads();
  float ls = 0.0f;
  for (int m = threadIdx.x; m < H; m += 256) ls += buf[m];
  float mean = blockSum<4>(ls, red) * (1.0f / H);
  float lv = 0.0f;
  for (int m = threadIdx.x; m < H; m += 256) {
    float d = buf[m] - mean;
    lv += d * d;
  }
  float var = blockSum<4>(lv, red) * (1.0f / H);
  float inv = rsqrtf(var + 1e-12f);
  for (int m = threadIdx.x; m < H; m += 256) {
    float v = (buf[m] - mean) * inv * g[m] + bb[m];
    size_t idx = (size_t)token * H + m;
    x[idx] = v;
    unsigned short hh, ll;
    split2(v, hh, ll);
    xh[idx] = (short)hh;
    xl[idx] = (short)ll;
  }
}

// ---------------- residual add + LN (emits fp32 + hi/lo) ----------------
__global__ __launch_bounds__(256) void add_ln_kernel(
    const float* __restrict__ a, const float* __restrict__ c,
    const float* __restrict__ g, const float* __restrict__ bb,
    float* __restrict__ out, short* __restrict__ oh, short* __restrict__ ol) {
  int token = blockIdx.x;
  __shared__ float buf[H];
  __shared__ float red[4];
  for (int m = threadIdx.x; m < H; m += 256)
    buf[m] = a[(size_t)token * H + m] + c[(size_t)token * H + m];
  __syncthreads();
  float ls = 0.0f;
  for (int m = threadIdx.x; m < H; m += 256) ls += buf[m];
  float mean = blockSum<4>(ls, red) * (1.0f / H);
  float lv = 0.0f;
  for (int m = threadIdx.x; m < H; m += 256) {
    float d = buf[m] - mean;
    lv += d * d;
  }
  float var = blockSum<4>(lv, red) * (1.0f / H);
  float inv = rsqrtf(var + 1e-12f);
  for (int m = threadIdx.x; m < H; m += 256) {
    float v = (buf[m] - mean) * inv * g[m] + bb[m];
    size_t idx = (size_t)token * H + m;
    out[idx] = v;
    unsigned short hh, ll;
    split2(v, hh, ll);
    oh[idx] = (short)hh;
    ol[idx] = (short)ll;
  }
}

// ---------------- weight convert + transpose: W[K][N] fp32 -> Wt[N][K] bf16 hi/lo ----
__global__ __launch_bounds__(256) void wconv_kernel(
    const float* __restrict__ W, short* __restrict__ Whi, short* __restrict__ Wlo,
    int K, int N, size_t in_lstride, size_t out_lstride) {
  const float* Wl = W + (size_t)blockIdx.z * in_lstride;
  short* Oh = Whi + (size_t)blockIdx.z * out_lstride;
  short* Ol = Wlo + (size_t)blockIdx.z * out_lstride;
  int kt = blockIdx.y * 64, nt = blockIdx.x * 64;
  __shared__ short sh[64][66];
  __shared__ short sl[64][66];
  int tid = threadIdx.x;
#pragma unroll
  for (int i = 0; i < 16; i++) {
    int f = tid + i * 256;
    int kr = f >> 6, nc = f & 63;
    float v = Wl[(size_t)(kt + kr) * N + nt + nc];
    unsigned short hh, ll;
    split2(v, hh, ll);
    sh[nc][kr] = (short)hh;
    sl[nc][kr] = (short)ll;
  }
  __syncthreads();
#pragma unroll
  for (int i = 0; i < 4; i++) {
    int u = tid + i * 256;
    int n = u >> 4, kc = (u & 15) * 4;
    size_t oo = (size_t)(nt + n) * K + kt + kc;
    short4v vh = {sh[n][kc], sh[n][kc + 1], sh[n][kc + 2], sh[n][kc + 3]};
    short4v vl = {sl[n][kc], sl[n][kc + 1], sl[n][kc + 2], sl[n][kc + 3]};
    *(short4v*)(Oh + oo) = vh;
    *(short4v*)(Ol + oo) = vl;
  }
}

// ---------------- MFMA GEMM: C = A @ W + bias via bf16 hi/lo 3-pass ----------------
// A as hi/lo bf16 [M][K]; B pre-transposed hi/lo bf16 [N][K]; bias fp32.
// act=0: write Cf fp32. act=1: exact GELU, write Chi/Clo bf16 split.
// Tile: 128x128 per block (4 waves, each 64x64 via 4x4 of 16x16x32 MFMA).
__global__ __launch_bounds__(256) void gemm_mfma(
    const short* __restrict__ Ahi, const short* __restrict__ Alo,
    const short* __restrict__ Bhi, const short* __restrict__ Blo,
    const float* __restrict__ bias, float* __restrict__ Cf,
    short* __restrict__ Chi, short* __restrict__ Clo,
    int M, int N, int K, int act) {
  constexpr int LDK = 40;  // padded row stride (shorts)
  __shared__ short sAh[128 * LDK], sAl[128 * LDK], sBh[128 * LDK], sBl[128 * LDK];
  int tid = threadIdx.x;
  int wave = tid >> 6, lane = tid & 63;
  int q = lane >> 4, r16 = lane & 15;
  int m0 = blockIdx.y * 128, n0 = blockIdx.x * 128;
  int wr = (wave >> 1) * 64, wc = (wave & 1) * 64;
  floatx4 acc[4][4];
#pragma unroll
  for (int i = 0; i < 4; i++)
#pragma unroll
    for (int j = 0; j < 4; j++) acc[i][j] = floatx4{0.f, 0.f, 0.f, 0.f};

  for (int k0 = 0; k0 < K; k0 += 32) {
    // stage 128x32 hi/lo chunks of A and B (each thread: 2 units of 8 shorts per array)
#pragma unroll
    for (int i = 0; i < 2; i++) {
      int u = tid + i * 256;
      int row = u >> 2, kc = (u & 3) * 8;
      size_t ga = (size_t)(m0 + row) * K + (k0 + kc);
      size_t gb = (size_t)(n0 + row) * K + (k0 + kc);
      int lof = row * LDK + kc;
      *(short8*)&sAh[lof] = *(const short8*)(Ahi + ga);
      *(short8*)&sAl[lof] = *(const short8*)(Alo + ga);
      *(short8*)&sBh[lof] = *(const short8*)(Bhi + gb);
      *(short8*)&sBl[lof] = *(const short8*)(Blo + gb);
    }
    __syncthreads();
    short8 ah[4], al[4], bh[4], bl[4];
#pragma unroll
    for (int mt = 0; mt < 4; mt++) {
      int off = (wr + mt * 16 + r16) * LDK + q * 8;
      ah[mt] = *(short8*)&sAh[off];
      al[mt] = *(short8*)&sAl[off];
    }
#pragma unroll
    for (int nt = 0; nt < 4; nt++) {
      int off = (wc + nt * 16 + r16) * LDK + q * 8;
      bh[nt] = *(short8*)&sBh[off];
      bl[nt] = *(short8*)&sBl[off];
    }
#pragma unroll
    for (int mt = 0; mt < 4; mt++)
#pragma unroll
      for (int nt = 0; nt < 4; nt++) {
        acc[mt][nt] = __builtin_amdgcn_mfma_f32_16x16x32_bf16(ah[mt], bh[nt], acc[mt][nt], 0, 0, 0);
        acc[mt][nt] = __builtin_amdgcn_mfma_f32_16x16x32_bf16(ah[mt], bl[nt], acc[mt][nt], 0, 0, 0);
        acc[mt][nt] = __builtin_amdgcn_mfma_f32_16x16x32_bf16(al[mt], bh[nt], acc[mt][nt], 0, 0, 0);
      }
    __syncthreads();
  }
  // epilogue: C/D layout col=lane&15, row=(lane>>4)*4+reg  [m89-verified]
#pragma unroll
  for (int nt = 0; nt < 4; nt++) {
    int col = n0 + wc + nt * 16 + r16;
    float bv = bias[col];
#pragma unroll
    for (int mt = 0; mt < 4; mt++) {
#pragma unroll
      for (int rr = 0; rr < 4; rr++) {
        int row = m0 + wr + mt * 16 + q * 4 + rr;
        float v = acc[mt][nt][rr] + bv;
        if (act) {
          v = 0.5f * v * (1.0f + erff(v * 0.7071067811865476f));
          unsigned short hh, ll;
          split2(v, hh, ll);
          Chi[(size_t)row * N + col] = (short)hh;
          Clo[(size_t)row * N + col] = (short)ll;
        } else {
          Cf[(size_t)row * N + col] = v;
        }
      }
    }
  }
}

// ---------------- attention: one block per (q, head, batch); emits hi/lo ----------
__global__ __launch_bounds__(128) void attn_kernel(
    const float* __restrict__ qkv, const int* __restrict__ amask,
    short* __restrict__ oh, short* __restrict__ ol) {
  int q = blockIdx.x, h = blockIdx.y, b = blockIdx.z;
  __shared__ float qv[DH];
  __shared__ float p[S];
  __shared__ float red[2];
  int tid = threadIdx.x;
  const float* base = qkv + (size_t)b * S * 3 * H;
  if (tid < DH) qv[tid] = base[(size_t)q * 3 * H + h * DH + tid];
  __syncthreads();
  const float* krow = base + (size_t)tid * 3 * H + H + h * DH;
  float sc = 0.0f;
#pragma unroll 16
  for (int d = 0; d < DH; d++) sc += qv[d] * krow[d];
  sc = sc * 0.125f + (amask[b * S + tid] ? 0.0f : -1e9f);
  float mx = blockMax<2>(sc, red);
  float e = expf(sc - mx);
  float sum = blockSum<2>(e, red);
  p[tid] = e / sum;
  __syncthreads();
  if (tid < DH) {
    const float* vb = base + 2 * H + h * DH + tid;
    float o = 0.0f;
    for (int j = 0; j < S; j++) o += p[j] * vb[(size_t)j * 3 * H];
    size_t idx = ((size_t)b * S + q) * H + h * DH + tid;
    unsigned short hh, ll;
    split2(o, hh, ll);
    oh[idx] = (short)hh;
    ol[idx] = (short)ll;
  }
}

// ---------------- conv1: block=(p-tile, o, b); weight row in LDS ----------------
__global__ __launch_bounds__(64) void conv1_kernel(
    const float* __restrict__ x, const float* __restrict__ w,
    const float* __restrict__ bias, float* __restrict__ c1) {
  int o = blockIdx.y, b = blockIdx.z;
  int p = blockIdx.x * 64 + threadIdx.x;
  __shared__ float wrow[SP * 5];
  for (int i = threadIdx.x; i < SP * 5; i += 64) wrow[i] = w[(size_t)o * SP * 5 + i];
  __syncthreads();
  if (p >= P1) return;
  const float* xb = x + ((size_t)b * S + 1) * H + 2 * p;
  float acc = bias[o];
  for (int i = 0; i < SP; i++) {
    const float* xr = xb + (size_t)i * H;
#pragma unroll
    for (int k = 0; k < 5; k++) acc += wrow[i * 5 + k] * xr[k];
  }
  c1[((size_t)b * SP + o) * P1 + p] = acc;
}

// ---------------- conv2: k=3, stride 2, dilation 2 ----------------
__global__ __launch_bounds__(64) void conv2_kernel(
    const float* __restrict__ c1, const float* __restrict__ w,
    const float* __restrict__ bias, float* __restrict__ c2) {
  int o = blockIdx.y, b = blockIdx.z;
  int p = blockIdx.x * 64 + threadIdx.x;
  __shared__ float wrow[SP * 3];
  for (int i = threadIdx.x; i < SP * 3; i += 64) wrow[i] = w[(size_t)o * SP * 3 + i];
  __syncthreads();
  if (p >= P2) return;
  const float* cb = c1 + (size_t)b * SP * P1 + 2 * p;
  float acc = bias[o];
  for (int i = 0; i < SP; i++) {
    const float* cr = cb + (size_t)i * P1;
#pragma unroll
    for (int k = 0; k < 3; k++) acc += wrow[i * 3 + k] * cr[2 * k];
  }
  c2[((size_t)b * SP + o) * P2 + p] = acc;
}

// ---------------- linear: (B*127,189) @ (189,9) + b ----------------
__global__ __launch_bounds__(64) void linear_kernel(
    const float* __restrict__ c2, const float* __restrict__ w,
    const float* __restrict__ bias, float* __restrict__ logits) {
  int row = blockIdx.x;
  int t = threadIdx.x;
  if (t < T) {
    const float* cr = c2 + (size_t)row * P2;
    float acc = bias[t];
    for (int p = 0; p < P2; p++) acc += cr[p] * w[p * T + t];
    logits[(size_t)row * T + t] = acc;
  }
}

// ---------------- CRF: forward-logsumexp + Viterbi + gold score, per batch ----------
__global__ __launch_bounds__(64) void crf_kernel(
    const float* __restrict__ em, const int* __restrict__ amask,
    const int* __restrict__ y, const float* __restrict__ start,
    const float* __restrict__ endv, const float* __restrict__ trans,
    float* __restrict__ path_out, float* __restrict__ part) {
  int b = blockIdx.x;
  int tid = threadIdx.x;
  __shared__ float sn[T], sv[T], nn[T], nv[T], e_sh[T];
  __shared__ float tr[T * T];
  __shared__ int hist[(SP - 1) * T];
  const float* eb = em + (size_t)b * SP * T;
  for (int i = tid; i < T * T; i += 64) tr[i] = trans[i];
  if (tid < T) {
    sn[tid] = start[tid] + eb[tid];
    sv[tid] = sn[tid];
  }
  __syncthreads();
  for (int t = 1; t < SP; t++) {
    int m = amask[b * S + t + 1];
    if (tid < T) e_sh[tid] = eb[t * T + tid];
    __syncthreads();
    if (tid < T) {
      int j = tid;
      float vals[T];
      float mx = -3.0e38f;
#pragma unroll
      for (int i = 0; i < T; i++) {
        float v = sn[i] + tr[i * T + j];
        vals[i] = v;
        mx = fmaxf(mx, v);
      }
      float sm = 0.0f;
#pragma unroll
      for (int i = 0; i < T; i++) sm += expf(vals[i] - mx);
      float ns = mx + logf(sm) + e_sh[j];
      float best = -3.0e38f;
      int bi = 0;
#pragma unroll
      for (int i = 0; i < T; i++) {
        float v = sv[i] + tr[i * T + j];
        if (v > best) { best = v; bi = i; }
      }
      float nvv = best + e_sh[j];
      nn[j] = m ? ns : sn[j];
      nv[j] = m ? nvv : sv[j];
      hist[(t - 1) * T + j] = m ? bi : j;
    }
    __syncthreads();
    if (tid < T) {
      sn[tid] = nn[tid];
      sv[tid] = nv[tid];
    }
    __syncthreads();
  }
  if (tid == 0) {
    float mx = -3.0e38f;
    for (int j = 0; j < T; j++) mx = fmaxf(mx, sn[j] + endv[j]);
    float sm = 0.0f;
    for (int j = 0; j < T; j++) sm += expf(sn[j] + endv[j] - mx);
    float norm = mx + logf(sm);
    float bestv = -3.0e38f;
    int last = 0;
    for (int j = 0; j < T; j++) {
      float v = sv[j] + endv[j];
      if (v > bestv) { bestv = v; last = j; }
    }
    int tag = last;
    for (int t = SP - 2; t >= 0; t--) {
      path_out[(size_t)b * SP + t + 1] = (float)tag;
      tag = hist[t * T + tag];
    }
    path_out[(size_t)b * SP] = (float)tag;
    const int* tg = y + b * SP;
    float sc = start[tg[0]] + eb[tg[0]];
    int length = 0;
    for (int t = 0; t < SP; t++) length += (amask[b * S + t + 1] != 0);
    for (int t = 1; t < SP; t++) {
      if (amask[b * S + t + 1])
        sc += tr[tg[t - 1] * T + tg[t]] + eb[t * T + tg[t]];
    }
    sc += endv[tg[length - 1]];
    part[b] = sc - norm;
  }
}

__global__ __launch_bounds__(64) void finalize_kernel(const float* __restrict__ part,
                                                      float* __restrict__ out) {
  float v = (threadIdx.x < B) ? part[threadIdx.x] : 0.0f;
  v = waveSum(v);
  if (threadIdx.x == 0) out[0] = v * (1.0f / B);
}

// ---------------- host launcher ----------------
extern "C" void kernel_launch(void* const* d_in, const int* in_sizes, int n_in,
                              void* d_out, int out_size, void* d_ws, size_t ws_size,
                              hipStream_t stream) {
  const int* input_ids = (const int*)d_in[0];
  const int* amask = (const int*)d_in[1];
  const int* tt = (const int*)d_in[2];
  const int* y_true = (const int*)d_in[3];
  const float* tok_emb = (const float*)d_in[4];
  const float* pos_emb = (const float*)d_in[5];
  const float* type_emb = (const float*)d_in[6];
  const float* emb_g = (const float*)d_in[7];
  const float* emb_b = (const float*)d_in[8];
  const float* Wqkv = (const float*)d_in[9];
  const float* bqkv = (const float*)d_in[10];
  const float* Wo = (const float*)d_in[11];
  const float* bo = (const float*)d_in[12];
  const float* ln1g = (const float*)d_in[13];
  const float* ln1b = (const float*)d_in[14];
  const float* Wff1 = (const float*)d_in[15];
  const float* bff1 = (const float*)d_in[16];
  const float* Wff2 = (const float*)d_in[17];
  const float* bff2 = (const float*)d_in[18];
  const float* ln2g = (const float*)d_in[19];
  const float* ln2b = (const float*)d_in[20];
  const float* c1w = (const float*)d_in[21];
  const float* c1b = (const float*)d_in[22];
  const float* c2w = (const float*)d_in[23];
  const float* c2b = (const float*)d_in[24];
  const float* lw = (const float*)d_in[25];
  const float* lb = (const float*)d_in[26];
  const float* crf_s = (const float*)d_in[27];
  const float* crf_e = (const float*)d_in[28];
  const float* crf_t = (const float*)d_in[29];

  const size_t BSH = (size_t)B * S * H;   // 3.1M
  const size_t BSF = (size_t)B * S * FF;  // 12.6M
  char* ws = (char*)d_ws;
  size_t off = 0;
  auto alloc = [&](size_t bytes) -> char* {
    char* p = ws + off;
    off = (off + bytes + 255) & ~(size_t)255;
    return p;
  };
  float* x = (float*)alloc(BSH * 4);
  short* xh = (short*)alloc(BSH * 2);
  short* xl = (short*)alloc(BSH * 2);
  short* ah = (short*)alloc(BSH * 2);  // also hh (liveness-disjoint)
  short* al = (short*)alloc(BSH * 2);  // also hl
  short* hh = ah;
  short* hl = al;
  float* hmid = (float*)alloc(BSH * 4);
  // arena A: qkv (fp32 [4096][2304]) / pf (fp32 [4096][768]) — liveness-disjoint
  char* arA = alloc(BSH * 3 * 4);
  float* qkv = (float*)arA;
  float* pf = (float*)arA;
  // arena B: gh/gl (bf16 [4096][3072] each) / conv+logits — liveness-disjoint
  char* arB = alloc(BSF * 2 * 2);
  short* gh = (short*)arB;
  short* gl = (short*)(arB + BSF * 2);
  float* c1 = (float*)arB;
  float* c2 = (float*)(arB + (size_t)B * SP * P1 * 4);
  float* logits = (float*)((char*)c2 + (size_t)B * SP * P2 * 4);
  float* part = (float*)alloc(1024);

  // converted+transposed weights, per-layer block layout: [qkv_t|wo_t|ff1_t|ff2_t]
  const size_t QKV_O = 0;
  const size_t WO_O = (size_t)H * 3 * H;            // 1769472
  const size_t FF1_O = WO_O + (size_t)H * H;        // 2359296
  const size_t FF2_O = FF1_O + (size_t)H * FF;      // 4718592
  const size_t WSZ = FF2_O + (size_t)FF * H;        // 7077888
  size_t base_need = off;
  bool full = (ws_size >= base_need + (size_t)L * WSZ * 4 + (1 << 20));
  short *wh, *wl;
  if (full) {
    wh = (short*)alloc((size_t)L * WSZ * 2);
    wl = (short*)alloc((size_t)L * WSZ * 2);
  } else {
    wh = (short*)alloc(WSZ * 2);
    wl = (short*)alloc(WSZ * 2);
  }
  float* outf = (float*)d_out;

  if (full) {  // convert all layers' weights up front (z = L)
    wconv_kernel<<<dim3(3 * H / 64, H / 64, L), 256, 0, stream>>>(
        Wqkv, wh + QKV_O, wl + QKV_O, H, 3 * H, (size_t)H * 3 * H, WSZ);
    wconv_kernel<<<dim3(H / 64, H / 64, L), 256, 0, stream>>>(
        Wo, wh + WO_O, wl + WO_O, H, H, (size_t)H * H, WSZ);
    wconv_kernel<<<dim3(FF / 64, H / 64, L), 256, 0, stream>>>(
        Wff1, wh + FF1_O, wl + FF1_O, H, FF, (size_t)H * FF, WSZ);
    wconv_kernel<<<dim3(H / 64, FF / 64, L), 256, 0, stream>>>(
        Wff2, wh + FF2_O, wl + FF2_O, FF, H, (size_t)FF * H, WSZ);
  }

  embed_ln_kernel<<<B * S, 256, 0, stream>>>(input_ids, tt, tok_emb, pos_emb,
                                             type_emb, emb_g, emb_b, x, xh, xl);
  const int M = B * S;  // 4096
  for (int l = 0; l < L; l++) {
    short* lwh = full ? wh + (size_t)l * WSZ : wh;
    short* lwl = full ? wl + (size_t)l * WSZ : wl;
    if (!full) {  // convert this layer's weights into the ping buffer
      wconv_kernel<<<dim3(3 * H / 64, H / 64, 1), 256, 0, stream>>>(
          Wqkv + (size_t)l * H * 3 * H, lwh + QKV_O, lwl + QKV_O, H, 3 * H, 0, 0);
      wconv_kernel<<<dim3(H / 64, H / 64, 1), 256, 0, stream>>>(
          Wo + (size_t)l * H * H, lwh + WO_O, lwl + WO_O, H, H, 0, 0);
      wconv_kernel<<<dim3(FF / 64, H / 64, 1), 256, 0, stream>>>(
          Wff1 + (size_t)l * H * FF, lwh + FF1_O, lwl + FF1_O, H, FF, 0, 0);
      wconv_kernel<<<dim3(H / 64, FF / 64, 1), 256, 0, stream>>>(
          Wff2 + (size_t)l * FF * H, lwh + FF2_O, lwl + FF2_O, FF, H, 0, 0);
    }
    gemm_mfma<<<dim3(3 * H / 128, M / 128), 256, 0, stream>>>(
        xh, xl, lwh + QKV_O, lwl + QKV_O, bqkv + (size_t)l * 3 * H, qkv,
        nullptr, nullptr, M, 3 * H, H, 0);
    attn_kernel<<<dim3(S, NH, B), 128, 0, stream>>>(qkv, amask, ah, al);
    gemm_mfma<<<dim3(H / 128, M / 128), 256, 0, stream>>>(
        ah, al, lwh + WO_O, lwl + WO_O, bo + (size_t)l * H, pf,
        nullptr, nullptr, M, H, H, 0);
    add_ln_kernel<<<B * S, 256, 0, stream>>>(x, pf, ln1g + (size_t)l * H,
                                             ln1b + (size_t)l * H, hmid, hh, hl);
    gemm_mfma<<<dim3(FF / 128, M / 128), 256, 0, stream>>>(
        hh, hl, lwh + FF1_O, lwl + FF1_O, bff1 + (size_t)l * FF, nullptr,
        gh, gl, M, FF, H, 1);
    gemm_mfma<<<dim3(H / 128, M / 128), 256, 0, stream>>>(
        gh, gl, lwh + FF2_O, lwl + FF2_O, bff2 + (size_t)l * H, pf,
        nullptr, nullptr, M, H, FF, 0);
    add_ln_kernel<<<B * S, 256, 0, stream>>>(hmid, pf, ln2g + (size_t)l * H,
                                             ln2b + (size_t)l * H, x, xh, xl);
  }
  conv1_kernel<<<dim3((P1 + 63) / 64, SP, B), 64, 0, stream>>>(x, c1w, c1b, c1);
  conv2_kernel<<<dim3((P2 + 63) / 64, SP, B), 64, 0, stream>>>(c1, c2w, c2b, c2);
  linear_kernel<<<B * SP, 64, 0, stream>>>(c2, lw, lb, logits);
  crf_kernel<<<B, 64, 0, stream>>>(logits, amask, y_true, crf_s, crf_e, crf_t,
                                   outf + 1, part);
  finalize_kernel<<<1, 64, 0, stream>>>(part, outf);
}